// Round 10
// baseline (632.196 us; speedup 1.0000x reference)
//
#include <hip/hip_runtime.h>
#include <hip/hip_cooperative_groups.h>
#include <math.h>

namespace cg = cooperative_groups;

// B=1, L=512, D=1024, NH=16, NKV=4, NR=16, HD=RD=64
#define ATTN_SCALE 0.125f
#define REL_SCALE 0.125f

using ushort = unsigned short;
using bf16x8 = __attribute__((ext_vector_type(8))) __bf16;
using floatx4 = __attribute__((ext_vector_type(4))) float;
using ushort8 = __attribute__((ext_vector_type(8))) ushort;
using ushort4v = __attribute__((ext_vector_type(4))) ushort;

__device__ __forceinline__ ushort f2bf(float x) {
  unsigned int u = __builtin_bit_cast(unsigned int, x);
  u += 0x7fffu + ((u >> 16) & 1u);  // RNE
  return (ushort)(u >> 16);
}

struct MegaArgs {
  const float *x, *symbols, *fcos, *fsin;
  const float *wq, *wk, *wqr, *wkr, *wr, *wv, *wo;
  float *out, *attn, *rel;
  ushort *wqT, *wkT, *wqrT, *wkrT, *wvT, *woT;
  ushort *qb, *kb, *qrb, *krb, *svT;
  float *asym;
  ushort *attb, *rel_bT, *attn_b;
};

// ===========================================================================
// Cooperative mega-kernel: 512 blocks (2/CU co-resident), 5 phases.
// ===========================================================================
__global__ __launch_bounds__(256, 2) void mega_kernel(MegaArgs p) {
  __shared__ __align__(16) char smem[49664];
  cg::grid_group grid = cg::this_grid();
  const int bx = blockIdx.x;
  const int tid = threadIdx.x;
  const int lane = tid & 63, wave = tid >> 6;
  const int lm = lane & 15, lq = lane >> 4;

  // ============ phase 1: weight transpose+convert (4608 32x32 tiles) ======
  {
    ushort(*t)[33] = (ushort(*)[33])smem;
    const int tx = tid & 31, ty = tid >> 5;
    for (int job = bx; job < 4608; job += 512) {
      const float* in;
      ushort* outp;
      int N, n0, k0;
      if (job < 4096) {
        int zi = job >> 10, tl = job & 1023;
        switch (zi) {
          case 0: in = p.wq;  outp = p.wqT;  break;
          case 1: in = p.wqr; outp = p.wqrT; break;
          case 2: in = p.wkr; outp = p.wkrT; break;
          default: in = p.wo; outp = p.woT;  break;
        }
        N = 1024; n0 = (tl & 31) << 5; k0 = (tl >> 5) << 5;
      } else {
        int j2 = job - 4096, zi = j2 >> 8, tl = j2 & 255;
        in = zi ? p.wv : p.wk;
        outp = zi ? p.wvT : p.wkT;
        N = 256; n0 = (tl & 7) << 5; k0 = (tl >> 3) << 5;
      }
      __syncthreads();
#pragma unroll
      for (int rr = 0; rr < 32; rr += 8)
        t[ty + rr][tx] = f2bf(in[(size_t)(k0 + ty + rr) * N + n0 + tx]);
      __syncthreads();
#pragma unroll
      for (int rr = 0; rr < 32; rr += 8)
        outp[(size_t)(n0 + ty + rr) * 1024 + k0 + tx] = t[tx][ty + rr];
    }
  }
  __threadfence();
  grid.sync();

  // ============ phase 2: projections (896 64x32 tiles) ====================
  {
    ushort(*As)[72] = (ushort(*)[72])smem;            // 64 rows
    ushort(*Bs)[72] = (ushort(*)[72])(smem + 9216);   // 32 rows
    const int sr = tid >> 2, sc = (tid & 3) << 4;
    const int br = tid >> 3, bc = (tid & 7) << 3;
    const int wy = (tid >> 7) & 1, wx = (tid >> 6) & 1;
    const ushort* a_rd = &As[32 * wy + lm][lq * 8];
    const ushort* b_rd = &Bs[16 * wx + lm][lq * 8];
    for (int job = bx; job < 896; job += 512) {
      int z, local;
      if (job < 256)      { z = 0; local = job; }
      else if (job < 320) { z = 1; local = job - 256; }
      else if (job < 576) { z = 2; local = job - 320; }
      else if (job < 832) { z = 3; local = job - 576; }
      else                { z = 4; local = job - 832; }
      const float* A = p.x;
      const ushort* Bt;
      ushort* C;
      int N, bnt, bmt;
      switch (z) {
        case 0: Bt = p.wqT;  C = p.qb;  N = 1024; bnt = local & 31; bmt = local >> 5; break;
        case 1: Bt = p.wkT;  C = p.kb;  N = 256;  bnt = local & 7;  bmt = local >> 3; break;
        case 2: Bt = p.wqrT; C = p.qrb; N = 1024; bnt = local & 31; bmt = local >> 5; break;
        case 3: Bt = p.wkrT; C = p.krb; N = 1024; bnt = local & 31; bmt = local >> 5; break;
        default: A = p.symbols; Bt = p.wvT; C = p.svT; N = 256; bnt = local & 7; bmt = local >> 3; break;
      }
      const int bn = bnt << 5, bm = bmt << 6;
      floatx4 acc[2] = {};
      for (int k0 = 0; k0 < 1024; k0 += 64) {
        const float* Ap = A + (size_t)(bm + sr) * 1024 + k0 + sc;
        float4 f0 = *(const float4*)(Ap);
        float4 f1 = *(const float4*)(Ap + 4);
        float4 f2 = *(const float4*)(Ap + 8);
        float4 f3 = *(const float4*)(Ap + 12);
        ushort8 av0 = ushort8{f2bf(f0.x), f2bf(f0.y), f2bf(f0.z), f2bf(f0.w),
                              f2bf(f1.x), f2bf(f1.y), f2bf(f1.z), f2bf(f1.w)};
        ushort8 av1 = ushort8{f2bf(f2.x), f2bf(f2.y), f2bf(f2.z), f2bf(f2.w),
                              f2bf(f3.x), f2bf(f3.y), f2bf(f3.z), f2bf(f3.w)};
        ushort8 bv = *(const ushort8*)(Bt + (size_t)(bn + br) * 1024 + k0 + bc);
        __syncthreads();
        *(ushort8*)&As[sr][sc] = av0;
        *(ushort8*)&As[sr][sc + 8] = av1;
        *(ushort8*)&Bs[br][bc] = bv;
        __syncthreads();
#pragma unroll
        for (int kh = 0; kh < 2; ++kh) {
          bf16x8 a0 = *(const bf16x8*)(a_rd + kh * 32);
          bf16x8 a1 = *(const bf16x8*)(a_rd + 16 * 72 + kh * 32);
          bf16x8 b0 = *(const bf16x8*)(b_rd + kh * 32);
          acc[0] = __builtin_amdgcn_mfma_f32_16x16x32_bf16(a0, b0, acc[0], 0, 0, 0);
          acc[1] = __builtin_amdgcn_mfma_f32_16x16x32_bf16(a1, b0, acc[1], 0, 0, 0);
        }
      }
      if (z <= 1) {
#pragma unroll
        for (int sy = 0; sy < 2; ++sy)
#pragma unroll
          for (int e = 0; e < 4; ++e) {
            int row = bm + 32 * wy + 16 * sy + 4 * lq + e;
            int col = bn + 16 * wx + lm;
            float v = acc[sy][e];
            float pv = __shfl_xor(v, 1);
            int d = col & 63, pp = d >> 1;
            float c = p.fcos[(row << 5) + pp], s = p.fsin[(row << 5) + pp];
            float o = (d & 1) ? fmaf(pv, s, v * c) : fmaf(v, c, -pv * s);
            C[(size_t)row * N + col] = f2bf(o);
          }
      } else if (z == 4) {
#pragma unroll
        for (int sy = 0; sy < 2; ++sy)
#pragma unroll
          for (int e = 0; e < 4; ++e) {
            int row = bm + 32 * wy + 16 * sy + 4 * lq + e;
            int col = bn + 16 * wx + lm;
            p.svT[(size_t)col * 512 + row] = f2bf(acc[sy][e]);
          }
      } else {
#pragma unroll
        for (int sy = 0; sy < 2; ++sy)
#pragma unroll
          for (int e = 0; e < 4; ++e) {
            int row = bm + 32 * wy + 16 * sy + 4 * lq + e;
            int col = bn + 16 * wx + lm;
            C[(size_t)row * N + col] = f2bf(acc[sy][e]);
          }
      }
    }
  }
  __threadfence();
  grid.sync();

  // ============ phase 3: flash (jobs 0..511) + relations (512..767) =======
  for (int job = bx; job < 768; job += 512) {
    if (job >= 512) {
      // ---- relations ----
      const int b = job - 512;
      const int bi0 = (b >> 4) << 5, bj0 = (b & 15) << 5;
      const int ib = bi0 + ((wave >> 1) << 4), jb = bj0 + ((wave & 1) << 4);
      const ushort* qrow = p.qrb + (size_t)(ib + lm) * 1024 + lq * 8;
      const ushort* krow = p.krb + (size_t)(jb + lm) * 1024 + lq * 8;
#pragma unroll
      for (int rq = 0; rq < 4; ++rq) {
        floatx4 acc[4];
#pragma unroll
        for (int rr = 0; rr < 4; ++rr) {
          int roff = ((rq << 2) + rr) << 6;
          bf16x8 a0 = *(const bf16x8*)(qrow + roff);
          bf16x8 a1 = *(const bf16x8*)(qrow + roff + 32);
          bf16x8 b0 = *(const bf16x8*)(krow + roff);
          bf16x8 b1 = *(const bf16x8*)(krow + roff + 32);
          floatx4 t = {0.f, 0.f, 0.f, 0.f};
          t = __builtin_amdgcn_mfma_f32_16x16x32_bf16(a0, b0, t, 0, 0, 0);
          t = __builtin_amdgcn_mfma_f32_16x16x32_bf16(a1, b1, t, 0, 0, 0);
          acc[rr] = t;
        }
#pragma unroll
        for (int e = 0; e < 4; ++e) {
          int i = ib + 4 * lq + e, j = jb + lm;
          float4 v = make_float4(acc[0][e] * REL_SCALE, acc[1][e] * REL_SCALE,
                                 acc[2][e] * REL_SCALE, acc[3][e] * REL_SCALE);
          *(float4*)(p.rel + ((size_t)i * 512 + j) * 16 + (rq << 2)) = v;
          size_t tb = (size_t)i * 8192 + (size_t)(rq << 2) * 512 + j;
          p.rel_bT[tb]        = f2bf(v.x);
          p.rel_bT[tb + 512]  = f2bf(v.y);
          p.rel_bT[tb + 1024] = f2bf(v.z);
          p.rel_bT[tb + 1536] = f2bf(v.w);
        }
      }
    } else {
      // ---- flash ----
      float(*S)[516] = (float(*)[516])smem;
      ushort(*P)[520] = (ushort(*)[520])(smem + 33024);
      const int h = job >> 5, it = 31 - (job & 31);
      const int i0 = it << 4, kv = h >> 2;
      const int ntiles = it + 1;
      const ushort* qrow = p.qb + (size_t)(i0 + lm) * 1024 + (h << 6) + lq * 8;
      bf16x8 a0 = *(const bf16x8*)(qrow);
      bf16x8 a1 = *(const bf16x8*)(qrow + 32);
      for (int jt = wave; jt < ntiles; jt += 4) {
        int jb = jt << 4;
        const ushort* krow = p.kb + (size_t)(jb + lm) * 256 + (kv << 6) + lq * 8;
        bf16x8 b0 = *(const bf16x8*)(krow);
        bf16x8 b1 = *(const bf16x8*)(krow + 32);
        floatx4 acc = {0.f, 0.f, 0.f, 0.f};
        acc = __builtin_amdgcn_mfma_f32_16x16x32_bf16(a0, b0, acc, 0, 0, 0);
        acc = __builtin_amdgcn_mfma_f32_16x16x32_bf16(a1, b1, acc, 0, 0, 0);
#pragma unroll
        for (int e = 0; e < 4; ++e) S[4 * lq + e][jb + lm] = acc[e] * ATTN_SCALE;
      }
      __syncthreads();
      const int row = tid >> 4, t16 = tid & 15;
      const int i = i0 + row;
      const int nj = ntiles << 4;
      float m = -INFINITY;
      for (int s = 0; (s << 6) < nj; ++s) {
        int j4 = (t16 << 2) + (s << 6);
        float4 v = *(const float4*)&S[row][j4];
        if (j4 + 0 <= i) m = fmaxf(m, v.x);
        if (j4 + 1 <= i) m = fmaxf(m, v.y);
        if (j4 + 2 <= i) m = fmaxf(m, v.z);
        if (j4 + 3 <= i) m = fmaxf(m, v.w);
      }
#pragma unroll
      for (int o = 8; o; o >>= 1) m = fmaxf(m, __shfl_xor(m, o, 16));
      float sum = 0.f;
      for (int s = 0; (s << 6) < nj; ++s) {
        int j4 = (t16 << 2) + (s << 6);
        float4 v = *(const float4*)&S[row][j4];
        v.x = (j4 + 0 <= i) ? __expf(v.x - m) : 0.f;
        v.y = (j4 + 1 <= i) ? __expf(v.y - m) : 0.f;
        v.z = (j4 + 2 <= i) ? __expf(v.z - m) : 0.f;
        v.w = (j4 + 3 <= i) ? __expf(v.w - m) : 0.f;
        sum += v.x + v.y + v.z + v.w;
        *(float4*)&S[row][j4] = v;
      }
#pragma unroll
      for (int o = 8; o; o >>= 1) sum += __shfl_xor(sum, o, 16);
      const float inv = 1.f / sum;
      float* arow = p.attn + (size_t)h * 262144 + (size_t)i * 512;
      ushort* abrow = p.attn_b + (size_t)i * 8192 + (size_t)h * 512;
      for (int s = 0; s < 8; ++s) {
        int j4 = (t16 << 2) + (s << 6);
        float4 o4 = {0.f, 0.f, 0.f, 0.f};
        if (j4 < nj) {
          float4 v = *(const float4*)&S[row][j4];
          o4.x = v.x * inv;
          o4.y = v.y * inv;
          o4.z = v.z * inv;
          o4.w = v.w * inv;
        }
        *(float4*)(arow + j4) = o4;  // exact zeros above diagonal
        ushort4v p4;
        p4.x = f2bf(o4.x); p4.y = f2bf(o4.y); p4.z = f2bf(o4.z); p4.w = f2bf(o4.w);
        *(ushort4v*)&P[row][j4] = p4;
        *(ushort4v*)(abrow + j4) = p4;
      }
      __syncthreads();
      const int dbase = wave << 4;
      floatx4 acc2 = {0.f, 0.f, 0.f, 0.f};
      const ushort* svrow = p.svT + (size_t)((kv << 6) + dbase + lm) * 512;
      const int kmax = (nj + 31) & ~31;
      for (int kt = 0; kt < kmax; kt += 32) {
        bf16x8 pa = *(const bf16x8*)&P[lm][kt + lq * 8];
        bf16x8 pb = *(const bf16x8*)(svrow + kt + lq * 8);
        acc2 = __builtin_amdgcn_mfma_f32_16x16x32_bf16(pa, pb, acc2, 0, 0, 0);
      }
#pragma unroll
      for (int e = 0; e < 4; ++e)
        p.asym[(size_t)(i0 + 4 * lq + e) * 1024 + (h << 6) + dbase + lm] = acc2[e];
      __syncthreads();
    }
  }
  __threadfence();
  grid.sync();

  // ============ phase 4: tker + combine (512 jobs, 1 i per block) =========
  {
    const int i = bx;
    float(*Ts)[16][17] = (float(*)[16][17])smem;
    floatx4 acc = {0.f, 0.f, 0.f, 0.f};
    const ushort* arow = p.attn_b + (size_t)i * 8192 + (size_t)lm * 512;  // h = lm
    const ushort* brow = p.rel_bT + (size_t)i * 8192 + (size_t)lm * 512;  // r = lm
    const int ktiles = (i >> 5) + 1;
    for (int kt = wave; kt < ktiles; kt += 4) {
      int k = (kt << 5) + lq * 8;
      bf16x8 a = *(const bf16x8*)(arow + k);
      bf16x8 b = *(const bf16x8*)(brow + k);
      acc = __builtin_amdgcn_mfma_f32_16x16x32_bf16(a, b, acc, 0, 0, 0);
    }
    __syncthreads();
#pragma unroll
    for (int e = 0; e < 4; ++e) Ts[wave][4 * lq + e][lm] = acc[e];
    __syncthreads();
    const int hc = tid >> 4, d4 = (tid & 15) << 2;
    float4 o = *(const float4*)(p.asym + (size_t)i * 1024 + (hc << 6) + d4);
#pragma unroll
    for (int rr = 0; rr < 16; ++rr) {
      float tv = Ts[0][hc][rr] + Ts[1][hc][rr] + Ts[2][hc][rr] + Ts[3][hc][rr];
      float4 w4 = *(const float4*)(p.wr + (size_t)rr * 1024 + (hc << 6) + d4);
      o.x = fmaf(tv, w4.x, o.x);
      o.y = fmaf(tv, w4.y, o.y);
      o.z = fmaf(tv, w4.z, o.z);
      o.w = fmaf(tv, w4.w, o.w);
    }
    ushort4v ob;
    ob.x = f2bf(o.x); ob.y = f2bf(o.y); ob.z = f2bf(o.z); ob.w = f2bf(o.w);
    *(ushort4v*)(p.attb + (size_t)i * 1024 + (hc << 6) + d4) = ob;
  }
  __threadfence();
  grid.sync();

  // ============ phase 5: out = attb @ wo (512 32x32 tiles) ================
  {
    ushort(*As)[72] = (ushort(*)[72])smem;
    ushort(*Bs)[72] = (ushort(*)[72])(smem + 4608);
    const int bn = (bx & 31) << 5, bm = (bx >> 5) << 5;
    const int sr = tid >> 3, sc = (tid & 7) << 3;
    const int wy = (tid >> 7) & 1, wx = (tid >> 6) & 1;
    const ushort* a_rd = &As[16 * wy + lm][lq * 8];
    const ushort* b_rd = &Bs[16 * wx + lm][lq * 8];
    floatx4 acc = {0.f, 0.f, 0.f, 0.f};
    for (int k0 = 0; k0 < 1024; k0 += 64) {
      ushort8 av = *(const ushort8*)(p.attb + (size_t)(bm + sr) * 1024 + k0 + sc);
      ushort8 bv = *(const ushort8*)(p.woT + (size_t)(bn + sr) * 1024 + k0 + sc);
      __syncthreads();
      *(ushort8*)&As[sr][sc] = av;
      *(ushort8*)&Bs[sr][sc] = bv;
      __syncthreads();
#pragma unroll
      for (int kh = 0; kh < 2; ++kh) {
        bf16x8 a0 = *(const bf16x8*)(a_rd + kh * 32);
        bf16x8 b0 = *(const bf16x8*)(b_rd + kh * 32);
        acc = __builtin_amdgcn_mfma_f32_16x16x32_bf16(a0, b0, acc, 0, 0, 0);
      }
    }
#pragma unroll
    for (int e = 0; e < 4; ++e) {
      int row = bm + 16 * wy + 4 * lq + e;
      int col = bn + 16 * wx + lm;
      p.out[(size_t)row * 1024 + col] = acc[e];
    }
  }
}

// ===========================================================================
// Fallback pipeline (R8, verbatim) — used if cooperative launch is refused.
// ===========================================================================
__global__ __launch_bounds__(256) void prep_kernel(
    const float* __restrict__ wq, const float* __restrict__ wk,
    const float* __restrict__ wqr, const float* __restrict__ wkr,
    const float* __restrict__ wv, const float* __restrict__ wo,
    ushort* __restrict__ wqT, ushort* __restrict__ wkT, ushort* __restrict__ wqrT,
    ushort* __restrict__ wkrT, ushort* __restrict__ wvT, ushort* __restrict__ woT) {
  __shared__ ushort t[32][33];
  const float* in;
  ushort* out;
  int N;
  switch (blockIdx.z) {
    case 0: in = wq;  out = wqT;  N = 1024; break;
    case 1: in = wk;  out = wkT;  N = 256;  break;
    case 2: in = wqr; out = wqrT; N = 1024; break;
    case 3: in = wkr; out = wkrT; N = 1024; break;
    case 4: in = wv;  out = wvT;  N = 256;  break;
    default: in = wo; out = woT;  N = 1024; break;
  }
  int n0 = blockIdx.x << 5;
  if (n0 >= N) return;
  int k0 = blockIdx.y << 5;
  int tx = threadIdx.x & 31, ty = threadIdx.x >> 5;
#pragma unroll
  for (int rr = 0; rr < 32; rr += 8)
    t[ty + rr][tx] = f2bf(in[(size_t)(k0 + ty + rr) * N + n0 + tx]);
  __syncthreads();
#pragma unroll
  for (int rr = 0; rr < 32; rr += 8)
    out[(size_t)(n0 + ty + rr) * 1024 + k0 + tx] = t[tx][ty + rr];
}

__global__ __launch_bounds__(256) void proj_mfma(
    const float* __restrict__ x, const float* __restrict__ symbols,
    const ushort* __restrict__ wqT, const ushort* __restrict__ wkT,
    const ushort* __restrict__ wqrT, const ushort* __restrict__ wkrT,
    const ushort* __restrict__ wvT,
    ushort* __restrict__ qb, ushort* __restrict__ kb, ushort* __restrict__ qrb,
    ushort* __restrict__ krb, ushort* __restrict__ svT,
    const float* __restrict__ fcos, const float* __restrict__ fsin) {
  __shared__ ushort As[64][72];
  __shared__ ushort Bs[32][72];
  const int z = blockIdx.z;
  const float* A = x;
  const ushort* Bt;
  ushort* C;
  int N;
  switch (z) {
    case 0: Bt = wqT;  C = qb;  N = 1024; break;
    case 1: Bt = wkT;  C = kb;  N = 256;  break;
    case 2: Bt = wqrT; C = qrb; N = 1024; break;
    case 3: Bt = wkrT; C = krb; N = 1024; break;
    default: A = symbols; Bt = wvT; C = svT; N = 256; break;
  }
  const int bn = blockIdx.x << 5;
  if (bn >= N) return;
  const int bm = blockIdx.y << 6;
  const int tid = threadIdx.x;
  const int sr = tid >> 2, sc = (tid & 3) << 4;
  const int br = tid >> 3, bc = (tid & 7) << 3;
  const int lane = tid & 63;
  const int wy = (tid >> 7) & 1, wx = (tid >> 6) & 1;
  const int lm = lane & 15, lq = lane >> 4;
  const ushort* a_rd = &As[32 * wy + lm][lq * 8];
  const ushort* b_rd = &Bs[16 * wx + lm][lq * 8];
  floatx4 acc[2] = {};
  for (int k0 = 0; k0 < 1024; k0 += 64) {
    const float* Ap = A + (size_t)(bm + sr) * 1024 + k0 + sc;
    float4 f0 = *(const float4*)(Ap);
    float4 f1 = *(const float4*)(Ap + 4);
    float4 f2 = *(const float4*)(Ap + 8);
    float4 f3 = *(const float4*)(Ap + 12);
    ushort8 av0 = ushort8{f2bf(f0.x), f2bf(f0.y), f2bf(f0.z), f2bf(f0.w),
                          f2bf(f1.x), f2bf(f1.y), f2bf(f1.z), f2bf(f1.w)};
    ushort8 av1 = ushort8{f2bf(f2.x), f2bf(f2.y), f2bf(f2.z), f2bf(f2.w),
                          f2bf(f3.x), f2bf(f3.y), f2bf(f3.z), f2bf(f3.w)};
    ushort8 bv = *(const ushort8*)(Bt + (size_t)(bn + br) * 1024 + k0 + bc);
    __syncthreads();
    *(ushort8*)&As[sr][sc] = av0;
    *(ushort8*)&As[sr][sc + 8] = av1;
    *(ushort8*)&Bs[br][bc] = bv;
    __syncthreads();
#pragma unroll
    for (int kh = 0; kh < 2; ++kh) {
      bf16x8 a0 = *(const bf16x8*)(a_rd + kh * 32);
      bf16x8 a1 = *(const bf16x8*)(a_rd + 16 * 72 + kh * 32);
      bf16x8 b0 = *(const bf16x8*)(b_rd + kh * 32);
      acc[0] = __builtin_amdgcn_mfma_f32_16x16x32_bf16(a0, b0, acc[0], 0, 0, 0);
      acc[1] = __builtin_amdgcn_mfma_f32_16x16x32_bf16(a1, b0, acc[1], 0, 0, 0);
    }
  }
  if (z <= 1) {
#pragma unroll
    for (int sy = 0; sy < 2; ++sy)
#pragma unroll
      for (int e = 0; e < 4; ++e) {
        int row = bm + 32 * wy + 16 * sy + 4 * lq + e;
        int col = bn + 16 * wx + lm;
        float v = acc[sy][e];
        float pv = __shfl_xor(v, 1);
        int d = col & 63, pp = d >> 1;
        float c = fcos[(row << 5) + pp], s = fsin[(row << 5) + pp];
        float o = (d & 1) ? fmaf(pv, s, v * c) : fmaf(v, c, -pv * s);
        C[(size_t)row * N + col] = f2bf(o);
      }
  } else if (z == 4) {
#pragma unroll
    for (int sy = 0; sy < 2; ++sy)
#pragma unroll
      for (int e = 0; e < 4; ++e) {
        int row = bm + 32 * wy + 16 * sy + 4 * lq + e;
        int col = bn + 16 * wx + lm;
        svT[(size_t)col * 512 + row] = f2bf(acc[sy][e]);
      }
  } else {
#pragma unroll
    for (int sy = 0; sy < 2; ++sy)
#pragma unroll
      for (int e = 0; e < 4; ++e) {
        int row = bm + 32 * wy + 16 * sy + 4 * lq + e;
        int col = bn + 16 * wx + lm;
        C[(size_t)row * N + col] = f2bf(acc[sy][e]);
      }
  }
}

__global__ __launch_bounds__(256) void relflash_kernel(
    const ushort* __restrict__ qb, const ushort* __restrict__ kb,
    const ushort* __restrict__ svT, const ushort* __restrict__ qrb,
    const ushort* __restrict__ krb, float* __restrict__ attn,
    ushort* __restrict__ attn_b, float* __restrict__ asym,
    float* __restrict__ rel, ushort* __restrict__ rel_bT) {
  __shared__ float S[16][516];
  __shared__ ushort P[16][520];
  const int bx = blockIdx.x;
  const int tid = threadIdx.x, wave = tid >> 6, lane = tid & 63;
  const int lm = lane & 15, lq = lane >> 4;
  if (bx >= 512) {
    const int b = bx - 512;
    const int bi0 = (b >> 4) << 5, bj0 = (b & 15) << 5;
    const int ib = bi0 + ((wave >> 1) << 4), jb = bj0 + ((wave & 1) << 4);
    const ushort* qrow = qrb + (size_t)(ib + lm) * 1024 + lq * 8;
    const ushort* krow = krb + (size_t)(jb + lm) * 1024 + lq * 8;
#pragma unroll
    for (int rq = 0; rq < 4; ++rq) {
      floatx4 acc[4];
#pragma unroll
      for (int rr = 0; rr < 4; ++rr) {
        int roff = ((rq << 2) + rr) << 6;
        bf16x8 a0 = *(const bf16x8*)(qrow + roff);
        bf16x8 a1 = *(const bf16x8*)(qrow + roff + 32);
        bf16x8 b0 = *(const bf16x8*)(krow + roff);
        bf16x8 b1 = *(const bf16x8*)(krow + roff + 32);
        floatx4 t = {0.f, 0.f, 0.f, 0.f};
        t = __builtin_amdgcn_mfma_f32_16x16x32_bf16(a0, b0, t, 0, 0, 0);
        t = __builtin_amdgcn_mfma_f32_16x16x32_bf16(a1, b1, t, 0, 0, 0);
        acc[rr] = t;
      }
#pragma unroll
      for (int e = 0; e < 4; ++e) {
        int i = ib + 4 * lq + e, j = jb + lm;
        float4 v = make_float4(acc[0][e] * REL_SCALE, acc[1][e] * REL_SCALE,
                               acc[2][e] * REL_SCALE, acc[3][e] * REL_SCALE);
        *(float4*)(rel + ((size_t)i * 512 + j) * 16 + (rq << 2)) = v;
        size_t tb = (size_t)i * 8192 + (size_t)(rq << 2) * 512 + j;
        rel_bT[tb]        = f2bf(v.x);
        rel_bT[tb + 512]  = f2bf(v.y);
        rel_bT[tb + 1024] = f2bf(v.z);
        rel_bT[tb + 1536] = f2bf(v.w);
      }
    }
    return;
  }
  const int h = bx >> 5, it = 31 - (bx & 31);
  const int i0 = it << 4, kv = h >> 2;
  const int ntiles = it + 1;
  const ushort* qrow = qb + (size_t)(i0 + lm) * 1024 + (h << 6) + lq * 8;
  bf16x8 a0 = *(const bf16x8*)(qrow);
  bf16x8 a1 = *(const bf16x8*)(qrow + 32);
  for (int jt = wave; jt < ntiles; jt += 4) {
    int jb = jt << 4;
    const ushort* krow = kb + (size_t)(jb + lm) * 256 + (kv << 6) + lq * 8;
    bf16x8 b0 = *(const bf16x8*)(krow);
    bf16x8 b1 = *(const bf16x8*)(krow + 32);
    floatx4 acc = {0.f, 0.f, 0.f, 0.f};
    acc = __builtin_amdgcn_mfma_f32_16x16x32_bf16(a0, b0, acc, 0, 0, 0);
    acc = __builtin_amdgcn_mfma_f32_16x16x32_bf16(a1, b1, acc, 0, 0, 0);
#pragma unroll
    for (int e = 0; e < 4; ++e) S[4 * lq + e][jb + lm] = acc[e] * ATTN_SCALE;
  }
  __syncthreads();
  const int row = tid >> 4, t16 = tid & 15;
  const int i = i0 + row;
  const int nj = ntiles << 4;
  float m = -INFINITY;
  for (int s = 0; (s << 6) < nj; ++s) {
    int j4 = (t16 << 2) + (s << 6);
    float4 v = *(const float4*)&S[row][j4];
    if (j4 + 0 <= i) m = fmaxf(m, v.x);
    if (j4 + 1 <= i) m = fmaxf(m, v.y);
    if (j4 + 2 <= i) m = fmaxf(m, v.z);
    if (j4 + 3 <= i) m = fmaxf(m, v.w);
  }
#pragma unroll
  for (int o = 8; o; o >>= 1) m = fmaxf(m, __shfl_xor(m, o, 16));
  float sum = 0.f;
  for (int s = 0; (s << 6) < nj; ++s) {
    int j4 = (t16 << 2) + (s << 6);
    float4 v = *(const float4*)&S[row][j4];
    v.x = (j4 + 0 <= i) ? __expf(v.x - m) : 0.f;
    v.y = (j4 + 1 <= i) ? __expf(v.y - m) : 0.f;
    v.z = (j4 + 2 <= i) ? __expf(v.z - m) : 0.f;
    v.w = (j4 + 3 <= i) ? __expf(v.w - m) : 0.f;
    sum += v.x + v.y + v.z + v.w;
    *(float4*)&S[row][j4] = v;
  }
#pragma unroll
  for (int o = 8; o; o >>= 1) sum += __shfl_xor(sum, o, 16);
  const float inv = 1.f / sum;
  float* arow = attn + (size_t)h * 262144 + (size_t)i * 512;
  ushort* abrow = attn_b + (size_t)i * 8192 + (size_t)h * 512;
  for (int s = 0; s < 8; ++s) {
    int j4 = (t16 << 2) + (s << 6);
    float4 o4 = {0.f, 0.f, 0.f, 0.f};
    if (j4 < nj) {
      float4 v = *(const float4*)&S[row][j4];
      o4.x = v.x * inv;
      o4.y = v.y * inv;
      o4.z = v.z * inv;
      o4.w = v.w * inv;
    }
    *(float4*)(arow + j4) = o4;
    ushort4v p4;
    p4.x = f2bf(o4.x); p4.y = f2bf(o4.y); p4.z = f2bf(o4.z); p4.w = f2bf(o4.w);
    *(ushort4v*)&P[row][j4] = p4;
    *(ushort4v*)(abrow + j4) = p4;
  }
  __syncthreads();
  const int dbase = wave << 4;
  floatx4 acc2 = {0.f, 0.f, 0.f, 0.f};
  const ushort* svrow = svT + (size_t)((kv << 6) + dbase + lm) * 512;
  const int kmax = (nj + 31) & ~31;
  for (int kt = 0; kt < kmax; kt += 32) {
    bf16x8 pa = *(const bf16x8*)&P[lm][kt + lq * 8];
    bf16x8 pb = *(const bf16x8*)(svrow + kt + lq * 8);
    acc2 = __builtin_amdgcn_mfma_f32_16x16x32_bf16(pa, pb, acc2, 0, 0, 0);
  }
#pragma unroll
  for (int e = 0; e < 4; ++e)
    asym[(size_t)(i0 + 4 * lq + e) * 1024 + (h << 6) + dbase + lm] = acc2[e];
}

__global__ __launch_bounds__(256) void tker_combine(const ushort* __restrict__ attn_b,
                                                    const ushort* __restrict__ rel_bT,
                                                    const float* __restrict__ asym,
                                                    const float* __restrict__ wr,
                                                    ushort* __restrict__ attb) {
  const int i = blockIdx.x;
  const int tid = threadIdx.x, wave = tid >> 6, lane = tid & 63;
  const int lm = lane & 15, lq = lane >> 4;
  __shared__ float Ts[4][16][17];
  floatx4 acc = {0.f, 0.f, 0.f, 0.f};
  const ushort* arow = attn_b + (size_t)i * 8192 + (size_t)lm * 512;
  const ushort* brow = rel_bT + (size_t)i * 8192 + (size_t)lm * 512;
  const int ktiles = (i >> 5) + 1;
  for (int kt = wave; kt < ktiles; kt += 4) {
    int k = (kt << 5) + lq * 8;
    bf16x8 a = *(const bf16x8*)(arow + k);
    bf16x8 b = *(const bf16x8*)(brow + k);
    acc = __builtin_amdgcn_mfma_f32_16x16x32_bf16(a, b, acc, 0, 0, 0);
  }
#pragma unroll
  for (int e = 0; e < 4; ++e) Ts[wave][4 * lq + e][lm] = acc[e];
  __syncthreads();
  const int hc = tid >> 4, d4 = (tid & 15) << 2;
  float4 o = *(const float4*)(asym + (size_t)i * 1024 + (hc << 6) + d4);
#pragma unroll
  for (int rr = 0; rr < 16; ++rr) {
    float tv = Ts[0][hc][rr] + Ts[1][hc][rr] + Ts[2][hc][rr] + Ts[3][hc][rr];
    float4 w4 = *(const float4*)(wr + (size_t)rr * 1024 + (hc << 6) + d4);
    o.x = fmaf(tv, w4.x, o.x);
    o.y = fmaf(tv, w4.y, o.y);
    o.z = fmaf(tv, w4.z, o.z);
    o.w = fmaf(tv, w4.w, o.w);
  }
  ushort4v ob;
  ob.x = f2bf(o.x); ob.y = f2bf(o.y); ob.z = f2bf(o.z); ob.w = f2bf(o.w);
  *(ushort4v*)(attb + (size_t)i * 1024 + (hc << 6) + d4) = ob;
}

__global__ __launch_bounds__(256) void out_mfma(const ushort* __restrict__ attb,
                                                const ushort* __restrict__ woT,
                                                float* __restrict__ out) {
  __shared__ ushort As[32][72];
  __shared__ ushort Bs[32][72];
  const int bn = blockIdx.x << 5, bm = blockIdx.y << 5;
  const int tid = threadIdx.x;
  const int sr = tid >> 3, sc = (tid & 7) << 3;
  const int lane = tid & 63;
  const int wy = (tid >> 7) & 1, wx = (tid >> 6) & 1;
  const int lm = lane & 15, lq = lane >> 4;
  const ushort* a_rd = &As[16 * wy + lm][lq * 8];
  const ushort* b_rd = &Bs[16 * wx + lm][lq * 8];
  floatx4 acc = {0.f, 0.f, 0.f, 0.f};
  for (int k0 = 0; k0 < 1024; k0 += 64) {
    ushort8 av = *(const ushort8*)(attb + (size_t)(bm + sr) * 1024 + k0 + sc);
    ushort8 bv = *(const ushort8*)(woT + (size_t)(bn + sr) * 1024 + k0 + sc);
    __syncthreads();
    *(ushort8*)&As[sr][sc] = av;
    *(ushort8*)&Bs[sr][sc] = bv;
    __syncthreads();
#pragma unroll
    for (int kh = 0; kh < 2; ++kh) {
      bf16x8 a0 = *(const bf16x8*)(a_rd + kh * 32);
      bf16x8 b0 = *(const bf16x8*)(b_rd + kh * 32);
      acc = __builtin_amdgcn_mfma_f32_16x16x32_bf16(a0, b0, acc, 0, 0, 0);
    }
  }
#pragma unroll
  for (int e = 0; e < 4; ++e) {
    int row = bm + 16 * wy + 4 * lq + e;
    int col = bn + 16 * wx + lm;
    out[(size_t)row * 1024 + col] = acc[e];
  }
}

extern "C" void kernel_launch(void* const* d_in, const int* in_sizes, int n_in,
                              void* d_out, int out_size, void* d_ws, size_t ws_size,
                              hipStream_t stream) {
  float* out  = (float*)d_out;   // 512*1024
  float* attn = out + 524288;    // 16*512*512
  float* rel  = attn + 4194304;  // 512*512*16

  char* wsb = (char*)d_ws;
  const size_t KB = 1024;
  MegaArgs p;
  p.x       = (const float*)d_in[0];
  p.symbols = (const float*)d_in[1];
  p.fcos    = (const float*)d_in[2];
  p.fsin    = (const float*)d_in[3];
  p.wq      = (const float*)d_in[4];
  p.wk      = (const float*)d_in[5];
  p.wqr     = (const float*)d_in[6];
  p.wkr     = (const float*)d_in[7];
  p.wr      = (const float*)d_in[8];
  p.wv      = (const float*)d_in[9];
  p.wo      = (const float*)d_in[10];
  p.out = out; p.attn = attn; p.rel = rel;
  p.wqT    = (ushort*)(wsb);                 // 2 MB
  p.wkT    = (ushort*)(wsb + 2048 * KB);     // 0.5 MB
  p.wqrT   = (ushort*)(wsb + 2560 * KB);     // 2 MB
  p.wkrT   = (ushort*)(wsb + 4608 * KB);     // 2 MB
  p.wvT    = (ushort*)(wsb + 6656 * KB);     // 0.5 MB
  p.woT    = (ushort*)(wsb + 7168 * KB);     // 2 MB
  p.qb     = (ushort*)(wsb + 9216 * KB);     // 1 MB
  p.kb     = (ushort*)(wsb + 10240 * KB);    // 0.25 MB
  p.qrb    = (ushort*)(wsb + 10496 * KB);    // 1 MB
  p.krb    = (ushort*)(wsb + 11520 * KB);    // 1 MB
  p.svT    = (ushort*)(wsb + 12544 * KB);    // 0.25 MB
  p.asym   = (float*)(wsb + 12800 * KB);     // 2 MB
  p.attb   = (ushort*)(wsb + 14848 * KB);    // 1 MB
  p.rel_bT = (ushort*)(wsb + 15872 * KB);    // 8 MB
  p.attn_b = (ushort*)(wsb + 24064 * KB);    // 8 MB

  void* args[] = { &p };
  hipError_t err = hipLaunchCooperativeKernel((void*)mega_kernel, dim3(512),
                                              dim3(256), args, 0, stream);
  if (err != hipSuccess) {
    (void)hipGetLastError();  // clear sticky error; use the 5-kernel pipeline
    prep_kernel<<<dim3(32, 32, 6), 256, 0, stream>>>(p.wq, p.wk, p.wqr, p.wkr,
                                                     p.wv, p.wo, p.wqT, p.wkT,
                                                     p.wqrT, p.wkrT, p.wvT, p.woT);
    proj_mfma<<<dim3(32, 8, 5), 256, 0, stream>>>(p.x, p.symbols, p.wqT, p.wkT,
                                                  p.wqrT, p.wkrT, p.wvT, p.qb, p.kb,
                                                  p.qrb, p.krb, p.svT, p.fcos, p.fsin);
    relflash_kernel<<<dim3(768), 256, 0, stream>>>(p.qb, p.kb, p.svT, p.qrb, p.krb,
                                                   p.attn, p.attn_b, p.asym, p.rel,
                                                   p.rel_bT);
    tker_combine<<<dim3(512), 256, 0, stream>>>(p.attn_b, p.rel_bT, p.asym, p.wr,
                                                p.attb);
    out_mfma<<<dim3(32, 16), 256, 0, stream>>>(p.attb, p.woT, p.out);
  }
}

// Round 11
// 173.107 us; speedup vs baseline: 3.6520x; 3.6520x over previous
//
#include <hip/hip_runtime.h>
#include <math.h>

// B=1, L=512, D=1024, NH=16, NKV=4, NR=16, HD=RD=64
#define ATTN_SCALE 0.125f
#define REL_SCALE 0.125f

using ushort = unsigned short;
using bf16x8 = __attribute__((ext_vector_type(8))) __bf16;
using floatx4 = __attribute__((ext_vector_type(4))) float;
using ushort8 = __attribute__((ext_vector_type(8))) ushort;
using ushort4v = __attribute__((ext_vector_type(4))) ushort;

__device__ __forceinline__ ushort f2bf(float x) {
  unsigned int u = __builtin_bit_cast(unsigned int, x);
  u += 0x7fffu + ((u >> 16) & 1u);  // RNE
  return (ushort)(u >> 16);
}

// ---------------------------------------------------------------------------
// prep: z=0..5 weight transpose+convert (conflict-free 32x33 LDS transpose);
//       z=6 x/symbols fp32->bf16
// ---------------------------------------------------------------------------
__global__ __launch_bounds__(256) void prep_kernel(
    const float* __restrict__ x, const float* __restrict__ sym,
    const float* __restrict__ wq, const float* __restrict__ wk,
    const float* __restrict__ wqr, const float* __restrict__ wkr,
    const float* __restrict__ wv, const float* __restrict__ wo,
    ushort* __restrict__ xb, ushort* __restrict__ symb,
    ushort* __restrict__ wqT, ushort* __restrict__ wkT, ushort* __restrict__ wqrT,
    ushort* __restrict__ wkrT, ushort* __restrict__ wvT, ushort* __restrict__ woT) {
  if (blockIdx.z == 6) {
    int b = blockIdx.y * 32 + blockIdx.x;
    if (b >= 512) return;
    int idx = b * 256 + threadIdx.x;
    int i4 = idx << 2;
    float4 v = *(const float4*)(x + i4);
    uint2 o;
    o.x = (unsigned)f2bf(v.x) | ((unsigned)f2bf(v.y) << 16);
    o.y = (unsigned)f2bf(v.z) | ((unsigned)f2bf(v.w) << 16);
    *(uint2*)(xb + i4) = o;
    float4 w = *(const float4*)(sym + i4);
    o.x = (unsigned)f2bf(w.x) | ((unsigned)f2bf(w.y) << 16);
    o.y = (unsigned)f2bf(w.z) | ((unsigned)f2bf(w.w) << 16);
    *(uint2*)(symb + i4) = o;
    return;
  }
  __shared__ ushort t[32][33];
  const float* in;
  ushort* out;
  int N;
  switch (blockIdx.z) {
    case 0: in = wq;  out = wqT;  N = 1024; break;
    case 1: in = wk;  out = wkT;  N = 256;  break;
    case 2: in = wqr; out = wqrT; N = 1024; break;
    case 3: in = wkr; out = wkrT; N = 1024; break;
    case 4: in = wv;  out = wvT;  N = 256;  break;
    default: in = wo; out = woT;  N = 1024; break;
  }
  int n0 = blockIdx.x << 5;
  if (n0 >= N) return;
  int k0 = blockIdx.y << 5;
  int tx = threadIdx.x & 31, ty = threadIdx.x >> 5;
#pragma unroll
  for (int rr = 0; rr < 32; rr += 8)
    t[ty + rr][tx] = f2bf(in[(size_t)(k0 + ty + rr) * N + n0 + tx]);
  __syncthreads();
#pragma unroll
  for (int rr = 0; rr < 32; rr += 8)
    out[(size_t)(n0 + ty + rr) * 1024 + k0 + tx] = t[tx][ty + rr];
}

// ---------------------------------------------------------------------------
// proj (LDS-free): each wave owns an independent 32x32 C tile, MFMA fragments
// loaded directly from global (lane lm = row, lq*8 = k) — the pattern the
// relations path uses. No barriers; occupancy VGPR-bound (~7 waves/CU free).
// 1792 wave-tiles over z = {q(+rope), k(+rope), qr, kr, sv(->svT)}.
// ---------------------------------------------------------------------------
__global__ __launch_bounds__(256) void proj_direct(
    const ushort* __restrict__ xb, const ushort* __restrict__ symb,
    const ushort* __restrict__ wqT, const ushort* __restrict__ wkT,
    const ushort* __restrict__ wqrT, const ushort* __restrict__ wkrT,
    const ushort* __restrict__ wvT,
    ushort* __restrict__ qb, ushort* __restrict__ kb, ushort* __restrict__ qrb,
    ushort* __restrict__ krb, ushort* __restrict__ svT,
    const float* __restrict__ fcos, const float* __restrict__ fsin) {
  const int tid = threadIdx.x, wave = tid >> 6, lane = tid & 63;
  const int lm = lane & 15, lq = lane >> 4;
  const int t = blockIdx.x * 4 + wave;  // 0..1791
  const ushort* A = xb;
  const ushort* Bt;
  ushort* C;
  int N, lo, ecase;  // ecase: 0=rope, 1=plain, 2=svT
  if (t < 512)       { Bt = wqT;  C = qb;  N = 1024; lo = t;        ecase = 0; }
  else if (t < 640)  { Bt = wkT;  C = kb;  N = 256;  lo = t - 512;  ecase = 0; }
  else if (t < 1152) { Bt = wqrT; C = qrb; N = 1024; lo = t - 640;  ecase = 1; }
  else if (t < 1664) { Bt = wkrT; C = krb; N = 1024; lo = t - 1152; ecase = 1; }
  else               { A = symb; Bt = wvT; C = svT; N = 256; lo = t - 1664; ecase = 2; }
  int wm, wn;
  if (N == 1024) { wm = (lo >> 5) << 5; wn = (lo & 31) << 5; }
  else           { wm = (lo >> 3) << 5; wn = (lo & 7) << 5; }

  const ushort* arow0 = A + (size_t)(wm + lm) * 1024 + lq * 8;
  const ushort* arow1 = arow0 + 16 * 1024;
  const ushort* brow0 = Bt + (size_t)(wn + lm) * 1024 + lq * 8;
  const ushort* brow1 = brow0 + 16 * 1024;
  floatx4 acc[2][2] = {};
  for (int k = 0; k < 1024; k += 32) {
    bf16x8 a0 = *(const bf16x8*)(arow0 + k);
    bf16x8 a1 = *(const bf16x8*)(arow1 + k);
    bf16x8 b0 = *(const bf16x8*)(brow0 + k);
    bf16x8 b1 = *(const bf16x8*)(brow1 + k);
    acc[0][0] = __builtin_amdgcn_mfma_f32_16x16x32_bf16(a0, b0, acc[0][0], 0, 0, 0);
    acc[0][1] = __builtin_amdgcn_mfma_f32_16x16x32_bf16(a0, b1, acc[0][1], 0, 0, 0);
    acc[1][0] = __builtin_amdgcn_mfma_f32_16x16x32_bf16(a1, b0, acc[1][0], 0, 0, 0);
    acc[1][1] = __builtin_amdgcn_mfma_f32_16x16x32_bf16(a1, b1, acc[1][1], 0, 0, 0);
  }
  if (ecase == 0) {
    // fused RoPE: lanes lm, lm^1 hold the (even,odd) pair of d
#pragma unroll
    for (int sy = 0; sy < 2; ++sy)
#pragma unroll
      for (int sx = 0; sx < 2; ++sx)
#pragma unroll
        for (int e = 0; e < 4; ++e) {
          int row = wm + 16 * sy + 4 * lq + e;
          int col = wn + 16 * sx + lm;
          float v = acc[sy][sx][e];
          float pv = __shfl_xor(v, 1);
          int d = col & 63, pp = d >> 1;
          float c = fcos[(row << 5) + pp], s = fsin[(row << 5) + pp];
          float o = (d & 1) ? fmaf(pv, s, v * c) : fmaf(v, c, -pv * s);
          C[(size_t)row * N + col] = f2bf(o);
        }
  } else if (ecase == 2) {
#pragma unroll
    for (int sy = 0; sy < 2; ++sy)
#pragma unroll
      for (int sx = 0; sx < 2; ++sx)
#pragma unroll
        for (int e = 0; e < 4; ++e) {
          int row = wm + 16 * sy + 4 * lq + e;
          int col = wn + 16 * sx + lm;
          svT[(size_t)col * 512 + row] = f2bf(acc[sy][sx][e]);
        }
  } else {
#pragma unroll
    for (int sy = 0; sy < 2; ++sy)
#pragma unroll
      for (int sx = 0; sx < 2; ++sx)
#pragma unroll
        for (int e = 0; e < 4; ++e) {
          int row = wm + 16 * sy + 4 * lq + e;
          int col = wn + 16 * sx + lm;
          C[(size_t)row * N + col] = f2bf(acc[sy][sx][e]);
        }
  }
}

// ---------------------------------------------------------------------------
// relflash: bx<512 -> flash (scores+softmax+attn fp32 + attn_b bf16 + asym);
//           bx>=512 -> relations (fp32 rel r-innermost + bf16 rel_bT[i][r][j]).
// ---------------------------------------------------------------------------
__global__ __launch_bounds__(256) void relflash_kernel(
    const ushort* __restrict__ qb, const ushort* __restrict__ kb,
    const ushort* __restrict__ svT, const ushort* __restrict__ qrb,
    const ushort* __restrict__ krb, float* __restrict__ attn,
    ushort* __restrict__ attn_b, float* __restrict__ asym,
    float* __restrict__ rel, ushort* __restrict__ rel_bT) {
  __shared__ float S[16][516];
  __shared__ ushort P[16][520];
  const int bx = blockIdx.x;
  const int tid = threadIdx.x, wave = tid >> 6, lane = tid & 63;
  const int lm = lane & 15, lq = lane >> 4;
  if (bx >= 512) {
    const int b = bx - 512;
    const int bi0 = (b >> 4) << 5, bj0 = (b & 15) << 5;
    const int ib = bi0 + ((wave >> 1) << 4), jb = bj0 + ((wave & 1) << 4);
    const ushort* qrow = qrb + (size_t)(ib + lm) * 1024 + lq * 8;
    const ushort* krow = krb + (size_t)(jb + lm) * 1024 + lq * 8;
#pragma unroll
    for (int rq = 0; rq < 4; ++rq) {
      floatx4 acc[4];
#pragma unroll
      for (int rr = 0; rr < 4; ++rr) {
        int roff = ((rq << 2) + rr) << 6;
        bf16x8 a0 = *(const bf16x8*)(qrow + roff);
        bf16x8 a1 = *(const bf16x8*)(qrow + roff + 32);
        bf16x8 b0 = *(const bf16x8*)(krow + roff);
        bf16x8 b1 = *(const bf16x8*)(krow + roff + 32);
        floatx4 t = {0.f, 0.f, 0.f, 0.f};
        t = __builtin_amdgcn_mfma_f32_16x16x32_bf16(a0, b0, t, 0, 0, 0);
        t = __builtin_amdgcn_mfma_f32_16x16x32_bf16(a1, b1, t, 0, 0, 0);
        acc[rr] = t;
      }
#pragma unroll
      for (int e = 0; e < 4; ++e) {
        int i = ib + 4 * lq + e, j = jb + lm;
        float4 v = make_float4(acc[0][e] * REL_SCALE, acc[1][e] * REL_SCALE,
                               acc[2][e] * REL_SCALE, acc[3][e] * REL_SCALE);
        *(float4*)(rel + ((size_t)i * 512 + j) * 16 + (rq << 2)) = v;
        size_t tb = (size_t)i * 8192 + (size_t)(rq << 2) * 512 + j;
        rel_bT[tb]        = f2bf(v.x);
        rel_bT[tb + 512]  = f2bf(v.y);
        rel_bT[tb + 1024] = f2bf(v.z);
        rel_bT[tb + 1536] = f2bf(v.w);
      }
    }
    return;
  }
  const int h = bx >> 5, it = 31 - (bx & 31);  // longest tiles dispatched first
  const int i0 = it << 4, kv = h >> 2;
  const int ntiles = it + 1;
  const ushort* qrow = qb + (size_t)(i0 + lm) * 1024 + (h << 6) + lq * 8;
  bf16x8 a0 = *(const bf16x8*)(qrow);
  bf16x8 a1 = *(const bf16x8*)(qrow + 32);
  for (int jt = wave; jt < ntiles; jt += 4) {
    int jb = jt << 4;
    const ushort* krow = kb + (size_t)(jb + lm) * 256 + (kv << 6) + lq * 8;
    bf16x8 b0 = *(const bf16x8*)(krow);
    bf16x8 b1 = *(const bf16x8*)(krow + 32);
    floatx4 acc = {0.f, 0.f, 0.f, 0.f};
    acc = __builtin_amdgcn_mfma_f32_16x16x32_bf16(a0, b0, acc, 0, 0, 0);
    acc = __builtin_amdgcn_mfma_f32_16x16x32_bf16(a1, b1, acc, 0, 0, 0);
#pragma unroll
    for (int e = 0; e < 4; ++e) S[4 * lq + e][jb + lm] = acc[e] * ATTN_SCALE;
  }
  __syncthreads();
  const int row = tid >> 4, t16 = tid & 15;
  const int i = i0 + row;
  const int nj = ntiles << 4;
  float m = -INFINITY;
  for (int s = 0; (s << 6) < nj; ++s) {
    int j4 = (t16 << 2) + (s << 6);
    float4 v = *(const float4*)&S[row][j4];
    if (j4 + 0 <= i) m = fmaxf(m, v.x);
    if (j4 + 1 <= i) m = fmaxf(m, v.y);
    if (j4 + 2 <= i) m = fmaxf(m, v.z);
    if (j4 + 3 <= i) m = fmaxf(m, v.w);
  }
#pragma unroll
  for (int o = 8; o; o >>= 1) m = fmaxf(m, __shfl_xor(m, o, 16));
  float sum = 0.f;
  for (int s = 0; (s << 6) < nj; ++s) {
    int j4 = (t16 << 2) + (s << 6);
    float4 v = *(const float4*)&S[row][j4];
    v.x = (j4 + 0 <= i) ? __expf(v.x - m) : 0.f;
    v.y = (j4 + 1 <= i) ? __expf(v.y - m) : 0.f;
    v.z = (j4 + 2 <= i) ? __expf(v.z - m) : 0.f;
    v.w = (j4 + 3 <= i) ? __expf(v.w - m) : 0.f;
    sum += v.x + v.y + v.z + v.w;
    *(float4*)&S[row][j4] = v;
  }
#pragma unroll
  for (int o = 8; o; o >>= 1) sum += __shfl_xor(sum, o, 16);
  const float inv = 1.f / sum;
  float* arow = attn + (size_t)h * 262144 + (size_t)i * 512;
  ushort* abrow = attn_b + (size_t)i * 8192 + (size_t)h * 512;
  for (int s = 0; s < 8; ++s) {
    int j4 = (t16 << 2) + (s << 6);
    float4 o4 = {0.f, 0.f, 0.f, 0.f};
    if (j4 < nj) {
      float4 v = *(const float4*)&S[row][j4];
      o4.x = v.x * inv;
      o4.y = v.y * inv;
      o4.z = v.z * inv;
      o4.w = v.w * inv;
    }
    *(float4*)(arow + j4) = o4;  // exact zeros above diagonal
    ushort4v p4;
    p4.x = f2bf(o4.x); p4.y = f2bf(o4.y); p4.z = f2bf(o4.z); p4.w = f2bf(o4.w);
    *(ushort4v*)&P[row][j4] = p4;
    *(ushort4v*)(abrow + j4) = p4;  // bf16 attn copy for tker
  }
  __syncthreads();
  const int dbase = wave << 4;
  floatx4 acc2 = {0.f, 0.f, 0.f, 0.f};
  const ushort* svrow = svT + (size_t)((kv << 6) + dbase + lm) * 512;
  const int kmax = (nj + 31) & ~31;  // P zero-filled to 512
  for (int kt = 0; kt < kmax; kt += 32) {
    bf16x8 pa = *(const bf16x8*)&P[lm][kt + lq * 8];
    bf16x8 pb = *(const bf16x8*)(svrow + kt + lq * 8);
    acc2 = __builtin_amdgcn_mfma_f32_16x16x32_bf16(pa, pb, acc2, 0, 0, 0);
  }
#pragma unroll
  for (int e = 0; e < 4; ++e)
    asym[(size_t)(i0 + 4 * lq + e) * 1024 + (h << 6) + dbase + lm] = acc2[e];
}

// ---------------------------------------------------------------------------
// tker+combine via MFMA: per i (wave w -> i = 4*bx + w),
// T[16h x 16r] = attn_b[i] (16x512 bf16) * rel_bT[i]^T (16x512 bf16).
// Then att[i,h,d] = asym + sum_r T[h][r]*wr[r][h*64+d] via LDS Ts.
// ---------------------------------------------------------------------------
__global__ __launch_bounds__(256) void tker_combine(const ushort* __restrict__ attn_b,
                                                    const ushort* __restrict__ rel_bT,
                                                    const float* __restrict__ asym,
                                                    const float* __restrict__ wr,
                                                    ushort* __restrict__ attb) {
  const int i0 = blockIdx.x << 2;
  const int tid = threadIdx.x, wave = tid >> 6, lane = tid & 63;
  const int lm = lane & 15, lq = lane >> 4;
  const int i = i0 + wave;
  __shared__ float Ts[4][16][17];
  floatx4 acc = {0.f, 0.f, 0.f, 0.f};
  const ushort* arow = attn_b + (size_t)i * 8192 + (size_t)lm * 512;  // h = lm
  const ushort* brow = rel_bT + (size_t)i * 8192 + (size_t)lm * 512;  // r = lm
  const int ktiles = (i >> 5) + 1;  // attn_b is exactly 0 for j > i
  for (int kt = 0; kt < ktiles; ++kt) {
    int k = (kt << 5) + lq * 8;
    bf16x8 a = *(const bf16x8*)(arow + k);
    bf16x8 b = *(const bf16x8*)(brow + k);
    acc = __builtin_amdgcn_mfma_f32_16x16x32_bf16(a, b, acc, 0, 0, 0);
  }
#pragma unroll
  for (int e = 0; e < 4; ++e) Ts[wave][4 * lq + e][lm] = acc[e];
  __syncthreads();
  const int hc = tid >> 4, d4 = (tid & 15) << 2;
  float4 o[4];
#pragma unroll
  for (int iw = 0; iw < 4; ++iw)
    o[iw] = *(const float4*)(asym + (size_t)(i0 + iw) * 1024 + (hc << 6) + d4);
#pragma unroll
  for (int rr = 0; rr < 16; ++rr) {
    float4 w4 = *(const float4*)(wr + (size_t)rr * 1024 + (hc << 6) + d4);
#pragma unroll
    for (int iw = 0; iw < 4; ++iw) {
      float tv = Ts[iw][hc][rr];
      o[iw].x = fmaf(tv, w4.x, o[iw].x);
      o[iw].y = fmaf(tv, w4.y, o[iw].y);
      o[iw].z = fmaf(tv, w4.z, o[iw].z);
      o[iw].w = fmaf(tv, w4.w, o[iw].w);
    }
  }
#pragma unroll
  for (int iw = 0; iw < 4; ++iw) {
    ushort4v ob;
    ob.x = f2bf(o[iw].x); ob.y = f2bf(o[iw].y);
    ob.z = f2bf(o[iw].z); ob.w = f2bf(o[iw].w);
    *(ushort4v*)(attb + (size_t)(i0 + iw) * 1024 + (hc << 6) + d4) = ob;
  }
}

// ---------------------------------------------------------------------------
// out (LDS-free): each wave an independent 16x16 C tile, fragments direct
// from global; 2048 wave-tiles = 8 waves/CU, no barriers.
// ---------------------------------------------------------------------------
__global__ __launch_bounds__(256) void out_direct(const ushort* __restrict__ attb,
                                                  const ushort* __restrict__ woT,
                                                  float* __restrict__ out) {
  const int tid = threadIdx.x, wave = tid >> 6, lane = tid & 63;
  const int lm = lane & 15, lq = lane >> 4;
  const int t = blockIdx.x * 4 + wave;  // 0..2047
  const int wm = (t >> 6) << 4, wn = (t & 63) << 4;
  const ushort* arow = attb + (size_t)(wm + lm) * 1024 + lq * 8;
  const ushort* brow = woT + (size_t)(wn + lm) * 1024 + lq * 8;
  floatx4 acc = {0.f, 0.f, 0.f, 0.f};
  for (int k = 0; k < 1024; k += 32) {
    bf16x8 a = *(const bf16x8*)(arow + k);
    bf16x8 b = *(const bf16x8*)(brow + k);
    acc = __builtin_amdgcn_mfma_f32_16x16x32_bf16(a, b, acc, 0, 0, 0);
  }
#pragma unroll
  for (int e = 0; e < 4; ++e)
    out[(size_t)(wm + 4 * lq + e) * 1024 + wn + lm] = acc[e];
}

extern "C" void kernel_launch(void* const* d_in, const int* in_sizes, int n_in,
                              void* d_out, int out_size, void* d_ws, size_t ws_size,
                              hipStream_t stream) {
  const float* x       = (const float*)d_in[0];
  const float* symbols = (const float*)d_in[1];
  const float* fcos    = (const float*)d_in[2];
  const float* fsin    = (const float*)d_in[3];
  const float* wq_attn = (const float*)d_in[4];
  const float* wk_attn = (const float*)d_in[5];
  const float* wq_rel  = (const float*)d_in[6];
  const float* wk_rel  = (const float*)d_in[7];
  const float* wr      = (const float*)d_in[8];
  const float* wv      = (const float*)d_in[9];
  const float* wo      = (const float*)d_in[10];

  float* out  = (float*)d_out;   // 512*1024
  float* attn = out + 524288;    // 16*512*512
  float* rel  = attn + 4194304;  // 512*512*16

  char* wsb = (char*)d_ws;
  const size_t KB = 1024;
  ushort* xb     = (ushort*)(wsb);                 // 1 MB
  ushort* symb   = (ushort*)(wsb + 1024 * KB);     // 1 MB
  ushort* wqT    = (ushort*)(wsb + 2048 * KB);     // 2 MB
  ushort* wkT    = (ushort*)(wsb + 4096 * KB);     // 0.5 MB
  ushort* wqrT   = (ushort*)(wsb + 4608 * KB);     // 2 MB
  ushort* wkrT   = (ushort*)(wsb + 6656 * KB);     // 2 MB
  ushort* wvT    = (ushort*)(wsb + 8704 * KB);     // 0.5 MB
  ushort* woT    = (ushort*)(wsb + 9216 * KB);     // 2 MB
  ushort* qb     = (ushort*)(wsb + 11264 * KB);    // 1 MB
  ushort* kb     = (ushort*)(wsb + 12288 * KB);    // 0.25 MB
  ushort* qrb    = (ushort*)(wsb + 12544 * KB);    // 1 MB
  ushort* krb    = (ushort*)(wsb + 13568 * KB);    // 1 MB
  ushort* svT    = (ushort*)(wsb + 14592 * KB);    // 0.25 MB
  float*  asym   = (float*)(wsb + 14848 * KB);     // 2 MB
  ushort* attb   = (ushort*)(wsb + 16896 * KB);    // 1 MB
  ushort* rel_bT = (ushort*)(wsb + 17920 * KB);    // 8 MB
  ushort* attn_b = (ushort*)(wsb + 26112 * KB);    // 8 MB

  prep_kernel<<<dim3(32, 32, 7), 256, 0, stream>>>(x, symbols, wq_attn, wk_attn,
                                                   wq_rel, wk_rel, wv, wo,
                                                   xb, symb, wqT, wkT, wqrT, wkrT, wvT, woT);
  proj_direct<<<dim3(448), 256, 0, stream>>>(xb, symb, wqT, wkT, wqrT, wkrT, wvT,
                                             qb, kb, qrb, krb, svT, fcos, fsin);
  relflash_kernel<<<dim3(768), 256, 0, stream>>>(qb, kb, svT, qrb, krb, attn, attn_b,
                                                 asym, rel, rel_bT);
  tker_combine<<<dim3(128), 256, 0, stream>>>(attn_b, rel_bT, asym, wr, attb);
  out_direct<<<dim3(512), 256, 0, stream>>>(attb, woT, out);
}

// Round 12
// 153.777 us; speedup vs baseline: 4.1111x; 1.1257x over previous
//
#include <hip/hip_runtime.h>
#include <math.h>

// B=1, L=512, D=1024, NH=16, NKV=4, NR=16, HD=RD=64
#define ATTN_SCALE 0.125f
#define REL_SCALE 0.125f

using ushort = unsigned short;
using bf16x8 = __attribute__((ext_vector_type(8))) __bf16;
using floatx4 = __attribute__((ext_vector_type(4))) float;
using ushort8 = __attribute__((ext_vector_type(8))) ushort;
using ushort4v = __attribute__((ext_vector_type(4))) ushort;

__device__ __forceinline__ ushort f2bf(float x) {
  unsigned int u = __builtin_bit_cast(unsigned int, x);
  u += 0x7fffu + ((u >> 16) & 1u);  // RNE
  return (ushort)(u >> 16);
}

// ---------------------------------------------------------------------------
// prep: z=0..5 weight transpose+convert (conflict-free 32x33 LDS transpose);
//       z=6 x/symbols fp32->bf16
// ---------------------------------------------------------------------------
__global__ __launch_bounds__(256) void prep_kernel(
    const float* __restrict__ x, const float* __restrict__ sym,
    const float* __restrict__ wq, const float* __restrict__ wk,
    const float* __restrict__ wqr, const float* __restrict__ wkr,
    const float* __restrict__ wv, const float* __restrict__ wo,
    ushort* __restrict__ xb, ushort* __restrict__ symb,
    ushort* __restrict__ wqT, ushort* __restrict__ wkT, ushort* __restrict__ wqrT,
    ushort* __restrict__ wkrT, ushort* __restrict__ wvT, ushort* __restrict__ woT) {
  if (blockIdx.z == 6) {
    int b = blockIdx.y * 32 + blockIdx.x;
    if (b >= 512) return;
    int idx = b * 256 + threadIdx.x;
    int i4 = idx << 2;
    float4 v = *(const float4*)(x + i4);
    uint2 o;
    o.x = (unsigned)f2bf(v.x) | ((unsigned)f2bf(v.y) << 16);
    o.y = (unsigned)f2bf(v.z) | ((unsigned)f2bf(v.w) << 16);
    *(uint2*)(xb + i4) = o;
    float4 w = *(const float4*)(sym + i4);
    o.x = (unsigned)f2bf(w.x) | ((unsigned)f2bf(w.y) << 16);
    o.y = (unsigned)f2bf(w.z) | ((unsigned)f2bf(w.w) << 16);
    *(uint2*)(symb + i4) = o;
    return;
  }
  __shared__ ushort t[32][33];
  const float* in;
  ushort* out;
  int N;
  switch (blockIdx.z) {
    case 0: in = wq;  out = wqT;  N = 1024; break;
    case 1: in = wk;  out = wkT;  N = 256;  break;
    case 2: in = wqr; out = wqrT; N = 1024; break;
    case 3: in = wkr; out = wkrT; N = 1024; break;
    case 4: in = wv;  out = wvT;  N = 256;  break;
    default: in = wo; out = woT;  N = 1024; break;
  }
  int n0 = blockIdx.x << 5;
  if (n0 >= N) return;
  int k0 = blockIdx.y << 5;
  int tx = threadIdx.x & 31, ty = threadIdx.x >> 5;
#pragma unroll
  for (int rr = 0; rr < 32; rr += 8)
    t[ty + rr][tx] = f2bf(in[(size_t)(k0 + ty + rr) * N + n0 + tx]);
  __syncthreads();
#pragma unroll
  for (int rr = 0; rr < 32; rr += 8)
    out[(size_t)(n0 + ty + rr) * 1024 + k0 + tx] = t[tx][ty + rr];
}

// ---------------------------------------------------------------------------
// proj: 64x32 tiles, LDS-staged bf16 operands.
// z = {q(+rope), k(+rope), qr, kr, sv(->svT)}.
// ---------------------------------------------------------------------------
__global__ __launch_bounds__(256) void proj_mfma(
    const ushort* __restrict__ xb, const ushort* __restrict__ symb,
    const ushort* __restrict__ wqT, const ushort* __restrict__ wkT,
    const ushort* __restrict__ wqrT, const ushort* __restrict__ wkrT,
    const ushort* __restrict__ wvT,
    ushort* __restrict__ qb, ushort* __restrict__ kb, ushort* __restrict__ qrb,
    ushort* __restrict__ krb, ushort* __restrict__ svT,
    const float* __restrict__ fcos, const float* __restrict__ fsin) {
  __shared__ ushort As[64][72];
  __shared__ ushort Bs[32][72];
  const int z = blockIdx.z;
  const ushort* A = xb;
  const ushort* Bt;
  ushort* C;
  int N;
  switch (z) {
    case 0: Bt = wqT;  C = qb;  N = 1024; break;
    case 1: Bt = wkT;  C = kb;  N = 256;  break;
    case 2: Bt = wqrT; C = qrb; N = 1024; break;
    case 3: Bt = wkrT; C = krb; N = 1024; break;
    default: A = symb; Bt = wvT; C = svT; N = 256; break;
  }
  const int bn = blockIdx.x << 5;
  if (bn >= N) return;
  const int bm = blockIdx.y << 6;
  const int tid = threadIdx.x;
  const int sr = tid >> 2, sc = (tid & 3) << 4;  // A stage: 16 elems
  const int br = tid >> 3, bc = (tid & 7) << 3;  // B stage: 8 elems
  const int lane = tid & 63;
  const int wy = (tid >> 7) & 1, wx = (tid >> 6) & 1;
  const int lm = lane & 15, lq = lane >> 4;
  const ushort* a_rd = &As[32 * wy + lm][lq * 8];
  const ushort* b_rd = &Bs[16 * wx + lm][lq * 8];
  floatx4 acc[2] = {};
  for (int k0 = 0; k0 < 1024; k0 += 64) {
    const ushort* Ap = A + (size_t)(bm + sr) * 1024 + k0 + sc;
    ushort8 av0 = *(const ushort8*)Ap;
    ushort8 av1 = *(const ushort8*)(Ap + 8);
    ushort8 bv = *(const ushort8*)(Bt + (size_t)(bn + br) * 1024 + k0 + bc);
    __syncthreads();
    *(ushort8*)&As[sr][sc] = av0;
    *(ushort8*)&As[sr][sc + 8] = av1;
    *(ushort8*)&Bs[br][bc] = bv;
    __syncthreads();
#pragma unroll
    for (int kh = 0; kh < 2; ++kh) {
      bf16x8 a0 = *(const bf16x8*)(a_rd + kh * 32);
      bf16x8 a1 = *(const bf16x8*)(a_rd + 16 * 72 + kh * 32);
      bf16x8 b0 = *(const bf16x8*)(b_rd + kh * 32);
      acc[0] = __builtin_amdgcn_mfma_f32_16x16x32_bf16(a0, b0, acc[0], 0, 0, 0);
      acc[1] = __builtin_amdgcn_mfma_f32_16x16x32_bf16(a1, b0, acc[1], 0, 0, 0);
    }
  }
  if (z <= 1) {
    // fused RoPE: lanes lm, lm^1 hold the (even,odd) pair of d
#pragma unroll
    for (int sy = 0; sy < 2; ++sy)
#pragma unroll
      for (int e = 0; e < 4; ++e) {
        int row = bm + 32 * wy + 16 * sy + 4 * lq + e;
        int col = bn + 16 * wx + lm;
        float v = acc[sy][e];
        float pv = __shfl_xor(v, 1);
        int d = col & 63, p = d >> 1;
        float c = fcos[(row << 5) + p], s = fsin[(row << 5) + p];
        float o = (d & 1) ? fmaf(pv, s, v * c) : fmaf(v, c, -pv * s);
        C[(size_t)row * N + col] = f2bf(o);
      }
  } else if (z == 4) {
#pragma unroll
    for (int sy = 0; sy < 2; ++sy)
#pragma unroll
      for (int e = 0; e < 4; ++e) {
        int row = bm + 32 * wy + 16 * sy + 4 * lq + e;
        int col = bn + 16 * wx + lm;
        svT[(size_t)col * 512 + row] = f2bf(acc[sy][e]);
      }
  } else {
#pragma unroll
    for (int sy = 0; sy < 2; ++sy)
#pragma unroll
      for (int e = 0; e < 4; ++e) {
        int row = bm + 32 * wy + 16 * sy + 4 * lq + e;
        int col = bn + 16 * wx + lm;
        C[(size_t)row * N + col] = f2bf(acc[sy][e]);
      }
  }
}

// ---------------------------------------------------------------------------
// relflash: bx<512 -> flash (scores+softmax+attn fp32 + attn_b bf16 + asym);
//           bx>=512 -> relations (fp32 rel r-innermost + bf16 rel_bT[i][r][j]).
// ---------------------------------------------------------------------------
__global__ __launch_bounds__(256) void relflash_kernel(
    const ushort* __restrict__ qb, const ushort* __restrict__ kb,
    const ushort* __restrict__ svT, const ushort* __restrict__ qrb,
    const ushort* __restrict__ krb, float* __restrict__ attn,
    ushort* __restrict__ attn_b, float* __restrict__ asym,
    float* __restrict__ rel, ushort* __restrict__ rel_bT) {
  __shared__ float S[16][516];
  __shared__ ushort P[16][520];
  const int bx = blockIdx.x;
  const int tid = threadIdx.x, wave = tid >> 6, lane = tid & 63;
  const int lm = lane & 15, lq = lane >> 4;
  if (bx >= 512) {
    // ---- relations ----
    const int b = bx - 512;
    const int bi0 = (b >> 4) << 5, bj0 = (b & 15) << 5;
    const int ib = bi0 + ((wave >> 1) << 4), jb = bj0 + ((wave & 1) << 4);
    const ushort* qrow = qrb + (size_t)(ib + lm) * 1024 + lq * 8;
    const ushort* krow = krb + (size_t)(jb + lm) * 1024 + lq * 8;
#pragma unroll
    for (int rq = 0; rq < 4; ++rq) {
      floatx4 acc[4];
#pragma unroll
      for (int rr = 0; rr < 4; ++rr) {
        int roff = ((rq << 2) + rr) << 6;
        bf16x8 a0 = *(const bf16x8*)(qrow + roff);
        bf16x8 a1 = *(const bf16x8*)(qrow + roff + 32);
        bf16x8 b0 = *(const bf16x8*)(krow + roff);
        bf16x8 b1 = *(const bf16x8*)(krow + roff + 32);
        floatx4 t = {0.f, 0.f, 0.f, 0.f};
        t = __builtin_amdgcn_mfma_f32_16x16x32_bf16(a0, b0, t, 0, 0, 0);
        t = __builtin_amdgcn_mfma_f32_16x16x32_bf16(a1, b1, t, 0, 0, 0);
        acc[rr] = t;
      }
#pragma unroll
      for (int e = 0; e < 4; ++e) {
        int i = ib + 4 * lq + e, j = jb + lm;
        float4 v = make_float4(acc[0][e] * REL_SCALE, acc[1][e] * REL_SCALE,
                               acc[2][e] * REL_SCALE, acc[3][e] * REL_SCALE);
        *(float4*)(rel + ((size_t)i * 512 + j) * 16 + (rq << 2)) = v;
        size_t tb = (size_t)i * 8192 + (size_t)(rq << 2) * 512 + j;
        rel_bT[tb]        = f2bf(v.x);
        rel_bT[tb + 512]  = f2bf(v.y);
        rel_bT[tb + 1024] = f2bf(v.z);
        rel_bT[tb + 1536] = f2bf(v.w);
      }
    }
    return;
  }
  // ---- flash ----
  const int h = bx >> 5, it = 31 - (bx & 31);  // longest tiles dispatched first
  const int i0 = it << 4, kv = h >> 2;
  const int ntiles = it + 1;
  const ushort* qrow = qb + (size_t)(i0 + lm) * 1024 + (h << 6) + lq * 8;
  bf16x8 a0 = *(const bf16x8*)(qrow);
  bf16x8 a1 = *(const bf16x8*)(qrow + 32);
  for (int jt = wave; jt < ntiles; jt += 4) {
    int jb = jt << 4;
    const ushort* krow = kb + (size_t)(jb + lm) * 256 + (kv << 6) + lq * 8;
    bf16x8 b0 = *(const bf16x8*)(krow);
    bf16x8 b1 = *(const bf16x8*)(krow + 32);
    floatx4 acc = {0.f, 0.f, 0.f, 0.f};
    acc = __builtin_amdgcn_mfma_f32_16x16x32_bf16(a0, b0, acc, 0, 0, 0);
    acc = __builtin_amdgcn_mfma_f32_16x16x32_bf16(a1, b1, acc, 0, 0, 0);
#pragma unroll
    for (int e = 0; e < 4; ++e) S[4 * lq + e][jb + lm] = acc[e] * ATTN_SCALE;
  }
  __syncthreads();
  const int row = tid >> 4, t16 = tid & 15;
  const int i = i0 + row;
  const int nj = ntiles << 4;
  float m = -INFINITY;
  for (int s = 0; (s << 6) < nj; ++s) {
    int j4 = (t16 << 2) + (s << 6);
    float4 v = *(const float4*)&S[row][j4];
    if (j4 + 0 <= i) m = fmaxf(m, v.x);
    if (j4 + 1 <= i) m = fmaxf(m, v.y);
    if (j4 + 2 <= i) m = fmaxf(m, v.z);
    if (j4 + 3 <= i) m = fmaxf(m, v.w);
  }
#pragma unroll
  for (int o = 8; o; o >>= 1) m = fmaxf(m, __shfl_xor(m, o, 16));
  float sum = 0.f;
  for (int s = 0; (s << 6) < nj; ++s) {
    int j4 = (t16 << 2) + (s << 6);
    float4 v = *(const float4*)&S[row][j4];
    v.x = (j4 + 0 <= i) ? __expf(v.x - m) : 0.f;
    v.y = (j4 + 1 <= i) ? __expf(v.y - m) : 0.f;
    v.z = (j4 + 2 <= i) ? __expf(v.z - m) : 0.f;
    v.w = (j4 + 3 <= i) ? __expf(v.w - m) : 0.f;
    sum += v.x + v.y + v.z + v.w;
    *(float4*)&S[row][j4] = v;
  }
#pragma unroll
  for (int o = 8; o; o >>= 1) sum += __shfl_xor(sum, o, 16);
  const float inv = 1.f / sum;
  float* arow = attn + (size_t)h * 262144 + (size_t)i * 512;
  ushort* abrow = attn_b + (size_t)i * 8192 + (size_t)h * 512;
  for (int s = 0; s < 8; ++s) {
    int j4 = (t16 << 2) + (s << 6);
    float4 o4 = {0.f, 0.f, 0.f, 0.f};
    if (j4 < nj) {
      float4 v = *(const float4*)&S[row][j4];
      o4.x = v.x * inv;
      o4.y = v.y * inv;
      o4.z = v.z * inv;
      o4.w = v.w * inv;
    }
    *(float4*)(arow + j4) = o4;  // exact zeros above diagonal
    ushort4v p4;
    p4.x = f2bf(o4.x); p4.y = f2bf(o4.y); p4.z = f2bf(o4.z); p4.w = f2bf(o4.w);
    *(ushort4v*)&P[row][j4] = p4;
    *(ushort4v*)(abrow + j4) = p4;  // bf16 attn copy for tker
  }
  __syncthreads();
  // attended_symbols: wave w owns d-range w*16
  const int dbase = wave << 4;
  floatx4 acc2 = {0.f, 0.f, 0.f, 0.f};
  const ushort* svrow = svT + (size_t)((kv << 6) + dbase + lm) * 512;
  const int kmax = (nj + 31) & ~31;  // P zero-filled to 512
  for (int kt = 0; kt < kmax; kt += 32) {
    bf16x8 pa = *(const bf16x8*)&P[lm][kt + lq * 8];
    bf16x8 pb = *(const bf16x8*)(svrow + kt + lq * 8);
    acc2 = __builtin_amdgcn_mfma_f32_16x16x32_bf16(pa, pb, acc2, 0, 0, 0);
  }
#pragma unroll
  for (int e = 0; e < 4; ++e)
    asym[(size_t)(i0 + 4 * lq + e) * 1024 + (h << 6) + dbase + lm] = acc2[e];
}

// ---------------------------------------------------------------------------
// tker+combine via MFMA: per i (wave w -> i = 4*bx + w),
// T[16h x 16r] = attn_b[i] (16x512 bf16) * rel_bT[i]^T (16x512 bf16).
// Then att[i,h,d] = asym + sum_r T[h][r]*wr[r][h*64+d] via LDS Ts.
// ---------------------------------------------------------------------------
__global__ __launch_bounds__(256) void tker_combine(const ushort* __restrict__ attn_b,
                                                    const ushort* __restrict__ rel_bT,
                                                    const float* __restrict__ asym,
                                                    const float* __restrict__ wr,
                                                    ushort* __restrict__ attb) {
  const int i0 = blockIdx.x << 2;
  const int tid = threadIdx.x, wave = tid >> 6, lane = tid & 63;
  const int lm = lane & 15, lq = lane >> 4;
  const int i = i0 + wave;
  __shared__ float Ts[4][16][17];
  floatx4 acc = {0.f, 0.f, 0.f, 0.f};
  const ushort* arow = attn_b + (size_t)i * 8192 + (size_t)lm * 512;  // h = lm
  const ushort* brow = rel_bT + (size_t)i * 8192 + (size_t)lm * 512;  // r = lm
  const int ktiles = (i >> 5) + 1;  // attn_b is exactly 0 for j > i
  for (int kt = 0; kt < ktiles; ++kt) {
    int k = (kt << 5) + lq * 8;
    bf16x8 a = *(const bf16x8*)(arow + k);
    bf16x8 b = *(const bf16x8*)(brow + k);
    acc = __builtin_amdgcn_mfma_f32_16x16x32_bf16(a, b, acc, 0, 0, 0);
  }
  // C layout: col(lm)=r, row(4*lq+e)=h
#pragma unroll
  for (int e = 0; e < 4; ++e) Ts[wave][4 * lq + e][lm] = acc[e];
  __syncthreads();
  const int hc = tid >> 4, d4 = (tid & 15) << 2;
  float4 o[4];
#pragma unroll
  for (int iw = 0; iw < 4; ++iw)
    o[iw] = *(const float4*)(asym + (size_t)(i0 + iw) * 1024 + (hc << 6) + d4);
#pragma unroll
  for (int rr = 0; rr < 16; ++rr) {
    float4 w4 = *(const float4*)(wr + (size_t)rr * 1024 + (hc << 6) + d4);
#pragma unroll
    for (int iw = 0; iw < 4; ++iw) {
      float tv = Ts[iw][hc][rr];
      o[iw].x = fmaf(tv, w4.x, o[iw].x);
      o[iw].y = fmaf(tv, w4.y, o[iw].y);
      o[iw].z = fmaf(tv, w4.z, o[iw].z);
      o[iw].w = fmaf(tv, w4.w, o[iw].w);
    }
  }
#pragma unroll
  for (int iw = 0; iw < 4; ++iw) {
    ushort4v ob;
    ob.x = f2bf(o[iw].x); ob.y = f2bf(o[iw].y);
    ob.z = f2bf(o[iw].z); ob.w = f2bf(o[iw].w);
    *(ushort4v*)(attb + (size_t)(i0 + iw) * 1024 + (hc << 6) + d4) = ob;
  }
}

// ---------------------------------------------------------------------------
// out = attb @ wo: 64x32 tiles (256 blocks), bf16 operands (woT from prep).
// ---------------------------------------------------------------------------
__global__ __launch_bounds__(256) void out_mfma(const ushort* __restrict__ attb,
                                                const ushort* __restrict__ woT,
                                                float* __restrict__ out) {
  __shared__ ushort As[64][72];
  __shared__ ushort Bs[32][72];
  const int bn = blockIdx.x << 5, bm = blockIdx.y << 6;
  const int tid = threadIdx.x;
  const int sr = tid >> 2, sc = (tid & 3) << 4;
  const int br = tid >> 3, bc = (tid & 7) << 3;
  const int lane = tid & 63;
  const int wy = (tid >> 7) & 1, wx = (tid >> 6) & 1;
  const int lm = lane & 15, lq = lane >> 4;
  const ushort* a_rd = &As[32 * wy + lm][lq * 8];
  const ushort* b_rd = &Bs[16 * wx + lm][lq * 8];
  floatx4 acc[2] = {};
  for (int k0 = 0; k0 < 1024; k0 += 64) {
    const ushort* Ap = attb + (size_t)(bm + sr) * 1024 + k0 + sc;
    ushort8 av0 = *(const ushort8*)Ap;
    ushort8 av1 = *(const ushort8*)(Ap + 8);
    ushort8 bv = *(const ushort8*)(woT + (size_t)(bn + br) * 1024 + k0 + bc);
    __syncthreads();
    *(ushort8*)&As[sr][sc] = av0;
    *(ushort8*)&As[sr][sc + 8] = av1;
    *(ushort8*)&Bs[br][bc] = bv;
    __syncthreads();
#pragma unroll
    for (int kh = 0; kh < 2; ++kh) {
      bf16x8 a0 = *(const bf16x8*)(a_rd + kh * 32);
      bf16x8 a1 = *(const bf16x8*)(a_rd + 16 * 72 + kh * 32);
      bf16x8 b0 = *(const bf16x8*)(b_rd + kh * 32);
      acc[0] = __builtin_amdgcn_mfma_f32_16x16x32_bf16(a0, b0, acc[0], 0, 0, 0);
      acc[1] = __builtin_amdgcn_mfma_f32_16x16x32_bf16(a1, b0, acc[1], 0, 0, 0);
    }
  }
#pragma unroll
  for (int sy = 0; sy < 2; ++sy)
#pragma unroll
    for (int e = 0; e < 4; ++e) {
      int row = bm + 32 * wy + 16 * sy + 4 * lq + e;
      int col = bn + 16 * wx + lm;
      out[(size_t)row * 1024 + col] = acc[sy][e];
    }
}

extern "C" void kernel_launch(void* const* d_in, const int* in_sizes, int n_in,
                              void* d_out, int out_size, void* d_ws, size_t ws_size,
                              hipStream_t stream) {
  const float* x       = (const float*)d_in[0];
  const float* symbols = (const float*)d_in[1];
  const float* fcos    = (const float*)d_in[2];
  const float* fsin    = (const float*)d_in[3];
  const float* wq_attn = (const float*)d_in[4];
  const float* wk_attn = (const float*)d_in[5];
  const float* wq_rel  = (const float*)d_in[6];
  const float* wk_rel  = (const float*)d_in[7];
  const float* wr      = (const float*)d_in[8];
  const float* wv      = (const float*)d_in[9];
  const float* wo      = (const float*)d_in[10];

  float* out  = (float*)d_out;   // 512*1024
  float* attn = out + 524288;    // 16*512*512
  float* rel  = attn + 4194304;  // 512*512*16

  char* wsb = (char*)d_ws;
  const size_t KB = 1024;
  ushort* xb     = (ushort*)(wsb);                 // 1 MB
  ushort* symb   = (ushort*)(wsb + 1024 * KB);     // 1 MB
  ushort* wqT    = (ushort*)(wsb + 2048 * KB);     // 2 MB
  ushort* wkT    = (ushort*)(wsb + 4096 * KB);     // 0.5 MB
  ushort* wqrT   = (ushort*)(wsb + 4608 * KB);     // 2 MB
  ushort* wkrT   = (ushort*)(wsb + 6656 * KB);     // 2 MB
  ushort* wvT    = (ushort*)(wsb + 8704 * KB);     // 0.5 MB
  ushort* woT    = (ushort*)(wsb + 9216 * KB);     // 2 MB
  ushort* qb     = (ushort*)(wsb + 11264 * KB);    // 1 MB
  ushort* kb     = (ushort*)(wsb + 12288 * KB);    // 0.25 MB
  ushort* qrb    = (ushort*)(wsb + 12544 * KB);    // 1 MB
  ushort* krb    = (ushort*)(wsb + 13568 * KB);    // 1 MB
  ushort* svT    = (ushort*)(wsb + 14592 * KB);    // 0.25 MB
  float*  asym   = (float*)(wsb + 14848 * KB);     // 2 MB
  ushort* attb   = (ushort*)(wsb + 16896 * KB);    // 1 MB
  ushort* rel_bT = (ushort*)(wsb + 17920 * KB);    // 8 MB
  ushort* attn_b = (ushort*)(wsb + 26112 * KB);    // 8 MB

  prep_kernel<<<dim3(32, 32, 7), 256, 0, stream>>>(x, symbols, wq_attn, wk_attn,
                                                   wq_rel, wk_rel, wv, wo,
                                                   xb, symb, wqT, wkT, wqrT, wkrT, wvT, woT);
  proj_mfma<<<dim3(32, 8, 5), 256, 0, stream>>>(xb, symb, wqT, wkT, wqrT, wkrT, wvT,
                                                qb, kb, qrb, krb, svT, fcos, fsin);
  relflash_kernel<<<dim3(768), 256, 0, stream>>>(qb, kb, svT, qrb, krb, attn, attn_b,
                                                 asym, rel, rel_bT);
  tker_combine<<<dim3(128), 256, 0, stream>>>(attn_b, rel_bT, asym, wr, attb);
  out_mfma<<<dim3(32, 8), 256, 0, stream>>>(attb, woT, out);
}